// Round 1
// baseline (419.298 us; speedup 1.0000x reference)
//
#include <hip/hip_runtime.h>
#include <stdint.h>

#define KNBR 16

typedef float f32x4 __attribute__((ext_vector_type(4)));
typedef __bf16 bf16x8 __attribute__((ext_vector_type(8)));

union ABFrag { uint4 u; bf16x8 v; };

__device__ __forceinline__ uint32_t bf16_rne(float x) {
    uint32_t u = __float_as_uint(x);
    return (u + 0x7fffu + ((u >> 16) & 1u)) >> 16;
}
__device__ __forceinline__ float bf_lo(uint32_t p) { return __uint_as_float(p << 16); }
__device__ __forceinline__ float bf_hi(uint32_t p) { return __uint_as_float(p & 0xffff0000u); }

// searchsorted(BOUNDARIES=[1,2,4,8,16,32,64,128], d, side='left') == #(b < d)
// boundaries are 2^0..2^7: bucket = clamp(exp + (mantissa!=0), 0, 8)
__device__ __forceinline__ int bucket_of(float d) {
    uint32_t u = __float_as_uint(d);
    int e = (int)((u >> 23) & 0xff) - 127;
    int b = e + ((u & 0x7fffffu) != 0 ? 1 : 0);
    return min(max(b, 0), 8);
}

// ---------- prep: fp32 -> bf16 (pair-packed) embed table ----------
__global__ void k_cvt_bf16(const float* __restrict__ src, uint32_t* __restrict__ dst, int n_pairs) {
    int i = blockIdx.x * blockDim.x + threadIdx.x;
    int stride = gridDim.x * blockDim.x;
    for (; i < n_pairs; i += stride) {
        float2 v = ((const float2*)src)[i];
        dst[i] = bf16_rne(v.x) | (bf16_rne(v.y) << 16);
    }
}

// ---------- prep: pack Wcat=[W_self;W_nbr] (256x128) into MFMA B-fragment order ----------
// element o: i=o&7, lane=(o>>3)&63, nt=(o>>9)&7, ks=o>>12
// B[k][c] with k = ks*32 + (lane>>4)*8 + i, c = nt*16 + (lane&15)
__global__ void k_pack_w(const float* __restrict__ Ws, const float* __restrict__ Wn,
                         uint16_t* __restrict__ Bp, int* __restrict__ counter) {
    int o = blockIdx.x * blockDim.x + threadIdx.x;
    if (o == 0) *counter = 0;
    if (o >= 8 * 8 * 64 * 8) return;
    int i = o & 7, lane = (o >> 3) & 63, nt = (o >> 9) & 7, ks = o >> 12;
    int r = ks * 32 + (lane >> 4) * 8 + i;
    int c = nt * 16 + (lane & 15);
    float v = (r < 128) ? Ws[r * 128 + c] : Wn[(r - 128) * 128 + c];
    Bp[o] = (uint16_t)bf16_rne(v);
}

// ---------- fused main: gather + agg -> LDS (swizzled) -> MFMA GEMM -> bias+relu ----------
template <int USE_EBF>
__global__ __launch_bounds__(1024, 4) void k_main(
    const int* __restrict__ node_ids, const int* __restrict__ nbr_idx,
    const float* __restrict__ nbr_dist, const float* __restrict__ emb_f32,
    const uint32_t* __restrict__ emb_bf, const float* __restrict__ dist_table,
    const float* __restrict__ bias, const uint32_t* __restrict__ Bp,
    int* __restrict__ counter, float* __restrict__ out, int ntiles)
{
    __shared__ uint32_t As[16 * 16 * 128];   // 16 waves x 16 rows x 256 bf16 (128 uints), swizzled
    __shared__ float dtab[9 * 128];
    __shared__ float bsh[128];

    for (int t = threadIdx.x; t < 9 * 128; t += 1024) dtab[t] = dist_table[t];
    if (threadIdx.x < 128) bsh[threadIdx.x] = bias[threadIdx.x];
    __syncthreads();

    const int lane = threadIdx.x & 63;
    const int w = threadIdx.x >> 6;
    const int l_hi = lane >> 4;   // 0..3
    const int l_lo = lane & 15;   // 0..15
    uint32_t* Aw = As + w * (16 * 128);

    for (;;) {
        int tile0 = 0;
        if (lane == 0) tile0 = atomicAdd(counter, 1);
        const int tile = __shfl(tile0, 0);
        if (tile >= ntiles) break;

        // ---- gather phase: 16 nodes, per-wave LDS staging (no block barrier) ----
        #pragma unroll 1
        for (int j = 0; j < 16; ++j) {
            const int n = (tile << 4) + j;
            const int sw = (j & 7) << 2;          // XOR swizzle in uint units (byte<<4)
            const int nid = node_ids[n];
            uint32_t hp;
            if (USE_EBF) {
                hp = emb_bf[(size_t)nid * 64 + lane];
            } else {
                float2 hv = *(const float2*)(emb_f32 + (size_t)nid * 128 + 2 * lane);
                hp = bf16_rne(hv.x) | (bf16_rne(hv.y) << 16);
            }
            Aw[j * 128 + (lane ^ sw)] = hp;       // cols 0..127 = h

            float ax = 0.f, ay = 0.f;
            const int* nrow = nbr_idx + (size_t)n * KNBR;
            const float* drow = nbr_dist + (size_t)n * KNBR;
            #pragma unroll
            for (int k = 0; k < KNBR; ++k) {
                const int sn = node_ids[nrow[k]];
                const int bkt = bucket_of(drow[k]);
                if (USE_EBF) {
                    uint32_t p = emb_bf[(size_t)sn * 64 + lane];
                    ax += bf_lo(p); ay += bf_hi(p);
                } else {
                    float2 v = *(const float2*)(emb_f32 + (size_t)sn * 128 + 2 * lane);
                    ax += v.x; ay += v.y;
                }
                float2 dv = *(const float2*)(dtab + bkt * 128 + 2 * lane);
                ax += dv.x; ay += dv.y;
            }
            ax *= 0.0625f; ay *= 0.0625f;
            Aw[j * 128 + 64 + (lane ^ sw)] = bf16_rne(ax) | (bf16_rne(ay) << 16); // cols 128..255 = agg
        }

        asm volatile("s_waitcnt lgkmcnt(0)" ::: "memory");

        // ---- MFMA phase: 16 rows x 128 cols, K=256 ----
        f32x4 acc[8];
        #pragma unroll
        for (int t = 0; t < 8; ++t) acc[t] = (f32x4){0.f, 0.f, 0.f, 0.f};

        #pragma unroll
        for (int ks = 0; ks < 8; ++ks) {
            ABFrag a;  // A[row=l_lo][k = ks*32 + l_hi*8 + 0..7]
            a.u = *(const uint4*)(Aw + l_lo * 128 + ((ks * 16 + l_hi * 4) ^ ((l_lo & 7) << 2)));
            #pragma unroll
            for (int nt = 0; nt < 8; ++nt) {
                ABFrag b;  // packed, L2-hot
                b.u = ((const uint4*)Bp)[(ks * 8 + nt) * 64 + lane];
                acc[nt] = __builtin_amdgcn_mfma_f32_16x16x32_bf16(a.v, b.v, acc[nt], 0, 0, 0);
            }
        }

        // ---- epilogue: D layout col=lane&15, row=(lane>>4)*4+reg (m89-verified) ----
        const int row0 = (tile << 4) + l_hi * 4;
        #pragma unroll
        for (int nt = 0; nt < 8; ++nt) {
            const int col = nt * 16 + l_lo;
            const float bv = bsh[col];
            #pragma unroll
            for (int r = 0; r < 4; ++r) {
                float v = acc[nt][r] + bv;
                out[(size_t)(row0 + r) * 128 + col] = v > 0.f ? v : 0.f;
            }
        }
    }
}

// ---------- safety fallback (tiny ws / tail nodes) ----------
__global__ void k_naive(const int* __restrict__ node_ids, const int* __restrict__ nbr_idx,
                        const float* __restrict__ nbr_dist, const float* __restrict__ emb,
                        const float* __restrict__ dt, const float* __restrict__ Ws,
                        const float* __restrict__ Wn, const float* __restrict__ bias,
                        float* __restrict__ out, int base) {
    __shared__ float h[128], ag[128];
    const int nd = base + blockIdx.x;
    const int t = threadIdx.x;
    const int nid = node_ids[nd];
    float hv = emb[(size_t)nid * 128 + t];
    float a = 0.f;
    for (int k = 0; k < KNBR; ++k) {
        int sn = node_ids[nbr_idx[(size_t)nd * KNBR + k]];
        int bkt = bucket_of(nbr_dist[(size_t)nd * KNBR + k]);
        a += emb[(size_t)sn * 128 + t] + dt[bkt * 128 + t];
    }
    h[t] = hv; ag[t] = a * 0.0625f;
    __syncthreads();
    float s = bias[t];
    for (int d = 0; d < 128; ++d) s += h[d] * Ws[d * 128 + t] + ag[d] * Wn[d * 128 + t];
    out[(size_t)nd * 128 + t] = s > 0.f ? s : 0.f;
}

extern "C" void kernel_launch(void* const* d_in, const int* in_sizes, int n_in,
                              void* d_out, int out_size, void* d_ws, size_t ws_size,
                              hipStream_t stream) {
    const int* node_ids   = (const int*)d_in[0];
    const int* nbr_idx    = (const int*)d_in[1];
    const float* nbr_dist = (const float*)d_in[2];
    const float* emb      = (const float*)d_in[3];
    const float* dist_tab = (const float*)d_in[4];
    const float* Ws       = (const float*)d_in[5];
    const float* Wn       = (const float*)d_in[6];
    const float* bias     = (const float*)d_in[7];
    float* out = (float*)d_out;
    const int n = in_sizes[0];
    const int in_dim = in_sizes[3] / 128;

    const size_t offCnt = 65536;               // after 64KB packed-W
    const size_t offEbf = offCnt + 256;
    const size_t needB  = offEbf;
    const size_t needE  = offEbf + (size_t)in_dim * 128 * 2;

    if (ws_size < needB) {
        if (n > 0)
            k_naive<<<n, 128, 0, stream>>>(node_ids, nbr_idx, nbr_dist, emb, dist_tab, Ws, Wn, bias, out, 0);
        return;
    }
    uint16_t* Bp   = (uint16_t*)d_ws;
    int* counter   = (int*)((char*)d_ws + offCnt);
    uint32_t* ebf  = (uint32_t*)((char*)d_ws + offEbf);

    k_pack_w<<<128, 256, 0, stream>>>(Ws, Wn, Bp, counter);

    const int ntiles = n >> 4;
    const int rem = n & 15;
    if (ws_size >= needE) {
        k_cvt_bf16<<<2048, 256, 0, stream>>>(emb, ebf, in_dim * 64);
        if (ntiles > 0)
            k_main<1><<<256, 1024, 0, stream>>>(node_ids, nbr_idx, nbr_dist, emb, ebf,
                                                dist_tab, bias, (const uint32_t*)Bp, counter, out, ntiles);
    } else {
        if (ntiles > 0)
            k_main<0><<<256, 1024, 0, stream>>>(node_ids, nbr_idx, nbr_dist, emb, ebf,
                                                dist_tab, bias, (const uint32_t*)Bp, counter, out, ntiles);
    }
    if (rem > 0)
        k_naive<<<rem, 128, 0, stream>>>(node_ids, nbr_idx, nbr_dist, emb, dist_tab, Ws, Wn, bias, out, ntiles << 4);
}

// Round 2
// 195.156 us; speedup vs baseline: 2.1485x; 2.1485x over previous
//
#include <hip/hip_runtime.h>
#include <stdint.h>

#define KNBR 16

typedef float f32x4 __attribute__((ext_vector_type(4)));
typedef __bf16 bf16x8 __attribute__((ext_vector_type(8)));

union ABFrag { uint4 u; bf16x8 v; };

__device__ __forceinline__ uint32_t bf16_rne(float x) {
    uint32_t u = __float_as_uint(x);
    return (u + 0x7fffu + ((u >> 16) & 1u)) >> 16;
}
__device__ __forceinline__ float bf_lo(uint32_t p) { return __uint_as_float(p << 16); }
__device__ __forceinline__ float bf_hi(uint32_t p) { return __uint_as_float(p & 0xffff0000u); }

// searchsorted(BOUNDARIES=[1,2,4,8,16,32,64,128], d) = clamp(exp + (mant!=0), 0, 8)
__device__ __forceinline__ int bucket_of(float d) {
    uint32_t u = __float_as_uint(d);
    int e = (int)((u >> 23) & 0xff) - 127;
    int b = e + ((u & 0x7fffffu) != 0 ? 1 : 0);
    return min(max(b, 0), 8);
}

// ---------- prep: fp32 -> bf16 (pair-packed) embed table ----------
__global__ void k_cvt_bf16(const float* __restrict__ src, uint32_t* __restrict__ dst, int n_pairs) {
    int i = blockIdx.x * blockDim.x + threadIdx.x;
    int stride = gridDim.x * blockDim.x;
    for (; i < n_pairs; i += stride) {
        float2 v = ((const float2*)src)[i];
        dst[i] = bf16_rne(v.x) | (bf16_rne(v.y) << 16);
    }
}

// ---------- prep: pack Wcat=[W_self;W_nbr] (256x128) into MFMA B-fragment order ----------
__global__ void k_pack_w(const float* __restrict__ Ws, const float* __restrict__ Wn,
                         uint16_t* __restrict__ Bp, int* __restrict__ counter) {
    int o = blockIdx.x * blockDim.x + threadIdx.x;
    if (o == 0) *counter = 0;
    if (o >= 8 * 8 * 64 * 8) return;
    int i = o & 7, lane = (o >> 3) & 63, nt = (o >> 9) & 7, ks = o >> 12;
    int r = ks * 32 + (lane >> 4) * 8 + i;
    int c = nt * 16 + (lane & 15);
    float v = (r < 128) ? Ws[r * 128 + c] : Wn[(r - 128) * 128 + c];
    Bp[o] = (uint16_t)bf16_rne(v);
}

// ---------- fused main ----------
// LDS budget: As 16w*16r*132u = 135168B, Ew 16w*272u = 17408B, dtab 4608B, bias 512B
//   total = 157696 B  (< 160 KiB, 1 block/CU, 4 waves/SIMD)
#define A_STRIDE 132
template <int USE_EBF>
__global__ __launch_bounds__(1024, 4) void k_main(
    const int* __restrict__ node_ids, const int* __restrict__ nbr_idx,
    const float* __restrict__ nbr_dist, const float* __restrict__ emb_f32,
    const uint32_t* __restrict__ emb_bf, const float* __restrict__ dist_table,
    const float* __restrict__ bias, const uint32_t* __restrict__ Bp,
    int* __restrict__ counter, float* __restrict__ out, int ntiles)
{
    __shared__ uint32_t As[16 * 16 * A_STRIDE];
    __shared__ uint32_t Es[16 * 272];         // per wave: 256 packed (sn|bkt<<24) + 16 self ids
    __shared__ float dtab[9 * 128];
    __shared__ float bsh[128];

    for (int t = threadIdx.x; t < 9 * 128; t += 1024) dtab[t] = dist_table[t];
    if (threadIdx.x < 128) bsh[threadIdx.x] = bias[threadIdx.x];
    __syncthreads();

    const int lane = threadIdx.x & 63;
    const int w = threadIdx.x >> 6;
    const int l_hi = lane >> 4;   // 0..3
    const int l_lo = lane & 15;   // 0..15
    uint32_t* Aw = As + w * (16 * A_STRIDE);
    uint32_t* Ew = Es + w * 272;
    float* Fw = (float*)(As) + w * (16 * A_STRIDE);

    for (;;) {
        int tile0 = 0;
        if (lane == 0) tile0 = atomicAdd(counter, 1);
        const int tile = __shfl(tile0, 0);
        if (tile >= ntiles) break;

        // ---- phase A: translate all 256 neighbor indices in parallel ----
        {
            int4 nb = *(const int4*)(nbr_idx + (size_t)tile * 256 + lane * 4);
            float4 dd = *(const float4*)(nbr_dist + (size_t)tile * 256 + lane * 4);
            int s0 = node_ids[nb.x];
            int s1 = node_ids[nb.y];
            int s2 = node_ids[nb.z];
            int s3 = node_ids[nb.w];
            uint4 e;
            e.x = (uint32_t)s0 | ((uint32_t)bucket_of(dd.x) << 24);
            e.y = (uint32_t)s1 | ((uint32_t)bucket_of(dd.y) << 24);
            e.z = (uint32_t)s2 | ((uint32_t)bucket_of(dd.z) << 24);
            e.w = (uint32_t)s3 | ((uint32_t)bucket_of(dd.w) << 24);
            *(uint4*)(Ew + lane * 4) = e;
            if (lane < 16) Ew[256 + lane] = (uint32_t)node_ids[(size_t)tile * 16 + lane];
        }
        // (compiler inserts lgkmcnt between the ds_writes above and reads below)

        // ---- phase B: per node, 17 independent row gathers (high MLP) ----
        #pragma unroll 1
        for (int j = 0; j < 16; ++j) {
            const int sw = (j & 7) << 2;
            const int nid = (int)__builtin_amdgcn_readfirstlane(Ew[256 + j]);

            uint32_t e[KNBR];
            #pragma unroll
            for (int k = 0; k < KNBR; ++k) e[k] = Ew[j * 16 + k];

            uint32_t hp;
            uint32_t p[KNBR];
            float2 pf[2]; // unused in EBF path
            if (USE_EBF) {
                hp = emb_bf[(size_t)nid * 64 + lane];
                #pragma unroll
                for (int k = 0; k < KNBR; ++k) {
                    const int sn = (int)(__builtin_amdgcn_readfirstlane(e[k]) & 0xFFFFFFu);
                    p[k] = emb_bf[(size_t)sn * 64 + lane];
                }
            } else {
                float2 hv = *(const float2*)(emb_f32 + (size_t)nid * 128 + 2 * lane);
                hp = bf16_rne(hv.x) | (bf16_rne(hv.y) << 16);
            }

            float ax = 0.f, ay = 0.f;
            #pragma unroll
            for (int k = 0; k < KNBR; ++k) {
                const int bkt = (int)(__builtin_amdgcn_readfirstlane(e[k]) >> 24);
                float2 dv = *(const float2*)(dtab + bkt * 128 + 2 * lane);
                ax += dv.x; ay += dv.y;
            }
            if (USE_EBF) {
                #pragma unroll
                for (int k = 0; k < KNBR; ++k) { ax += bf_lo(p[k]); ay += bf_hi(p[k]); }
            } else {
                #pragma unroll
                for (int k = 0; k < KNBR; ++k) {
                    const int sn = (int)(__builtin_amdgcn_readfirstlane(e[k]) & 0xFFFFFFu);
                    float2 v = *(const float2*)(emb_f32 + (size_t)sn * 128 + 2 * lane);
                    ax += v.x; ay += v.y;
                }
            }
            ax *= 0.0625f; ay *= 0.0625f;
            Aw[j * A_STRIDE + (lane ^ sw)] = hp;                                  // cols 0..127 = h
            Aw[j * A_STRIDE + 64 + (lane ^ sw)] = bf16_rne(ax) | (bf16_rne(ay) << 16); // 128..255 = agg
            (void)pf;
        }

        // ---- MFMA phase: 16 rows x 128 cols, K=256 ----
        f32x4 acc[8];
        #pragma unroll
        for (int t = 0; t < 8; ++t) acc[t] = (f32x4){0.f, 0.f, 0.f, 0.f};

        #pragma unroll
        for (int ks = 0; ks < 8; ++ks) {
            ABFrag a;  // A[row=l_lo][k = ks*32 + l_hi*8 + 0..7]
            a.u = *(const uint4*)(Aw + l_lo * A_STRIDE + ((ks * 16 + l_hi * 4) ^ ((l_lo & 7) << 2)));
            #pragma unroll
            for (int nt = 0; nt < 8; ++nt) {
                ABFrag b;  // packed weights, L2-hot
                b.u = ((const uint4*)Bp)[(ks * 8 + nt) * 64 + lane];
                acc[nt] = __builtin_amdgcn_mfma_f32_16x16x32_bf16(a.v, b.v, acc[nt], 0, 0, 0);
            }
        }

        // ---- epilogue: bias+relu -> LDS (stride 132) -> coalesced full-line stores ----
        #pragma unroll
        for (int nt = 0; nt < 8; ++nt) {
            const int col = nt * 16 + l_lo;
            const float bv = bsh[col];
            #pragma unroll
            for (int r = 0; r < 4; ++r) {
                float v = acc[nt][r] + bv;
                Fw[(l_hi * 4 + r) * A_STRIDE + col] = v > 0.f ? v : 0.f;
            }
        }
        float* dst = out + (size_t)tile * 2048;
        #pragma unroll
        for (int it = 0; it < 8; ++it) {
            const int f = it * 256 + lane * 4;
            const int r = f >> 7, c = f & 127;
            float4 v = *(const float4*)(Fw + r * A_STRIDE + c);
            *(float4*)(dst + f) = v;
        }
    }
}

// ---------- safety fallback (tiny ws / tail nodes) ----------
__global__ void k_naive(const int* __restrict__ node_ids, const int* __restrict__ nbr_idx,
                        const float* __restrict__ nbr_dist, const float* __restrict__ emb,
                        const float* __restrict__ dt, const float* __restrict__ Ws,
                        const float* __restrict__ Wn, const float* __restrict__ bias,
                        float* __restrict__ out, int base) {
    __shared__ float h[128], ag[128];
    const int nd = base + blockIdx.x;
    const int t = threadIdx.x;
    const int nid = node_ids[nd];
    float hv = emb[(size_t)nid * 128 + t];
    float a = 0.f;
    for (int k = 0; k < KNBR; ++k) {
        int sn = node_ids[nbr_idx[(size_t)nd * KNBR + k]];
        int bkt = bucket_of(nbr_dist[(size_t)nd * KNBR + k]);
        a += emb[(size_t)sn * 128 + t] + dt[bkt * 128 + t];
    }
    h[t] = hv; ag[t] = a * 0.0625f;
    __syncthreads();
    float s = bias[t];
    for (int d = 0; d < 128; ++d) s += h[d] * Ws[d * 128 + t] + ag[d] * Wn[d * 128 + t];
    out[(size_t)nd * 128 + t] = s > 0.f ? s : 0.f;
}

extern "C" void kernel_launch(void* const* d_in, const int* in_sizes, int n_in,
                              void* d_out, int out_size, void* d_ws, size_t ws_size,
                              hipStream_t stream) {
    const int* node_ids   = (const int*)d_in[0];
    const int* nbr_idx    = (const int*)d_in[1];
    const float* nbr_dist = (const float*)d_in[2];
    const float* emb      = (const float*)d_in[3];
    const float* dist_tab = (const float*)d_in[4];
    const float* Ws       = (const float*)d_in[5];
    const float* Wn       = (const float*)d_in[6];
    const float* bias     = (const float*)d_in[7];
    float* out = (float*)d_out;
    const int n = in_sizes[0];
    const int in_dim = in_sizes[3] / 128;

    const size_t offCnt = 65536;               // after 64KB packed-W
    const size_t offEbf = offCnt + 256;
    const size_t needB  = offEbf;
    const size_t needE  = offEbf + (size_t)in_dim * 128 * 2;

    if (ws_size < needB) {
        if (n > 0)
            k_naive<<<n, 128, 0, stream>>>(node_ids, nbr_idx, nbr_dist, emb, dist_tab, Ws, Wn, bias, out, 0);
        return;
    }
    uint16_t* Bp   = (uint16_t*)d_ws;
    int* counter   = (int*)((char*)d_ws + offCnt);
    uint32_t* ebf  = (uint32_t*)((char*)d_ws + offEbf);

    k_pack_w<<<128, 256, 0, stream>>>(Ws, Wn, Bp, counter);

    const int ntiles = n >> 4;
    const int rem = n & 15;
    if (ws_size >= needE) {
        k_cvt_bf16<<<2048, 256, 0, stream>>>(emb, ebf, in_dim * 64);
        if (ntiles > 0)
            k_main<1><<<256, 1024, 0, stream>>>(node_ids, nbr_idx, nbr_dist, emb, ebf,
                                                dist_tab, bias, (const uint32_t*)Bp, counter, out, ntiles);
    } else {
        if (ntiles > 0)
            k_main<0><<<256, 1024, 0, stream>>>(node_ids, nbr_idx, nbr_dist, emb, ebf,
                                                dist_tab, bias, (const uint32_t*)Bp, counter, out, ntiles);
    }
    if (rem > 0)
        k_naive<<<rem, 128, 0, stream>>>(node_ids, nbr_idx, nbr_dist, emb, dist_tab, Ws, Wn, bias, out, ntiles << 4);
}

// Round 3
// 192.754 us; speedup vs baseline: 2.1753x; 1.0125x over previous
//
#include <hip/hip_runtime.h>
#include <stdint.h>

#define KNBR 16

typedef float f32x4 __attribute__((ext_vector_type(4)));
typedef float f32x2 __attribute__((ext_vector_type(2)));
typedef __bf16 bf16x8 __attribute__((ext_vector_type(8)));

union ABFrag { uint4 u; bf16x8 v; };

__device__ __forceinline__ uint32_t bf16_rne(float x) {
    uint32_t u = __float_as_uint(x);
    return (u + 0x7fffu + ((u >> 16) & 1u)) >> 16;
}
__device__ __forceinline__ float bf_lo(uint32_t p) { return __uint_as_float(p << 16); }
__device__ __forceinline__ float bf_hi(uint32_t p) { return __uint_as_float(p & 0xffff0000u); }

// searchsorted(BOUNDARIES=[1,2,4,8,16,32,64,128], d) = clamp(exp + (mant!=0), 0, 8)
__device__ __forceinline__ int bucket_of(float d) {
    uint32_t u = __float_as_uint(d);
    int e = (int)((u >> 23) & 0xff) - 127;
    int b = e + ((u & 0x7fffffu) != 0 ? 1 : 0);
    return min(max(b, 0), 8);
}

// ---------- prep: fp32 -> bf16 table AND fp8(e4m3) table in one read ----------
// dword i covers features [4i, 4i+4): ebf gets 2 dwords (bf16 pairs), e8 gets 1 dword (4 fp8)
__global__ void k_cvt_both(const float* __restrict__ src, uint32_t* __restrict__ ebf,
                           uint32_t* __restrict__ e8, int n_dwords) {
    int i = blockIdx.x * blockDim.x + threadIdx.x;
    int stride = gridDim.x * blockDim.x;
    for (; i < n_dwords; i += stride) {
        float4 v = ((const float4*)src)[i];
        ebf[2 * i]     = bf16_rne(v.x) | (bf16_rne(v.y) << 16);
        ebf[2 * i + 1] = bf16_rne(v.z) | (bf16_rne(v.w) << 16);
        uint32_t p = 0;
        p = __builtin_amdgcn_cvt_pk_fp8_f32(v.x, v.y, p, false);
        p = __builtin_amdgcn_cvt_pk_fp8_f32(v.z, v.w, p, true);
        e8[i] = p;
    }
}

// ---------- prep: pack Wcat=[W_self;W_nbr] (256x128) into MFMA B-fragment order ----------
__global__ void k_pack_w(const float* __restrict__ Ws, const float* __restrict__ Wn,
                         uint16_t* __restrict__ Bp, int* __restrict__ counter) {
    int o = blockIdx.x * blockDim.x + threadIdx.x;
    if (o == 0) *counter = 0;
    if (o >= 8 * 8 * 64 * 8) return;
    int i = o & 7, lane = (o >> 3) & 63, nt = (o >> 9) & 7, ks = o >> 12;
    int r = ks * 32 + (lane >> 4) * 8 + i;
    int c = nt * 16 + (lane & 15);
    float v = (r < 128) ? Ws[r * 128 + c] : Wn[(r - 128) * 128 + c];
    Bp[o] = (uint16_t)bf16_rne(v);
}

// ---------- fused main ----------
// MODE: 0 = f32 gathers (no ws tables), 1 = bf16 both, 2 = fp8 neighbors + bf16 self
#define A_STRIDE 132
template <int MODE>
__global__ __launch_bounds__(1024, 4) void k_main(
    const int* __restrict__ node_ids, const int* __restrict__ nbr_idx,
    const float* __restrict__ nbr_dist, const float* __restrict__ emb_f32,
    const uint32_t* __restrict__ emb_bf, const uint16_t* __restrict__ emb8,
    const float* __restrict__ dist_table, const float* __restrict__ bias,
    const uint32_t* __restrict__ Bp, int* __restrict__ counter,
    float* __restrict__ out, int ntiles)
{
    __shared__ uint32_t As[16 * 16 * A_STRIDE];
    __shared__ uint32_t Es[16 * 272];         // per wave: 256 packed (sn|bkt<<24) + 16 self ids
    __shared__ float dtab[9 * 128];
    __shared__ float bsh[128];

    for (int t = threadIdx.x; t < 9 * 128; t += 1024) dtab[t] = dist_table[t];
    if (threadIdx.x < 128) bsh[threadIdx.x] = bias[threadIdx.x];
    __syncthreads();

    const int lane = threadIdx.x & 63;
    const int w = threadIdx.x >> 6;
    const int l_hi = lane >> 4;   // 0..3
    const int l_lo = lane & 15;   // 0..15
    uint32_t* Aw = As + w * (16 * A_STRIDE);
    uint32_t* Ew = Es + w * 272;
    float* Fw = (float*)(As) + w * (16 * A_STRIDE);

    for (;;) {
        int tile0 = 0;
        if (lane == 0) tile0 = atomicAdd(counter, 1);
        const int tile = __shfl(tile0, 0);
        if (tile >= ntiles) break;

        // ---- phase A: translate all 256 neighbor indices in parallel ----
        {
            int4 nb = *(const int4*)(nbr_idx + (size_t)tile * 256 + lane * 4);
            float4 dd = *(const float4*)(nbr_dist + (size_t)tile * 256 + lane * 4);
            int s0 = node_ids[nb.x];
            int s1 = node_ids[nb.y];
            int s2 = node_ids[nb.z];
            int s3 = node_ids[nb.w];
            uint4 e;
            e.x = (uint32_t)s0 | ((uint32_t)bucket_of(dd.x) << 24);
            e.y = (uint32_t)s1 | ((uint32_t)bucket_of(dd.y) << 24);
            e.z = (uint32_t)s2 | ((uint32_t)bucket_of(dd.z) << 24);
            e.w = (uint32_t)s3 | ((uint32_t)bucket_of(dd.w) << 24);
            *(uint4*)(Ew + lane * 4) = e;
            if (lane < 16) Ew[256 + lane] = (uint32_t)node_ids[(size_t)tile * 16 + lane];
        }

        // ---- phase B: per node, 17 independent row gathers (high MLP) ----
        #pragma unroll 2
        for (int j = 0; j < 16; ++j) {
            const int sw = (j & 7) << 2;
            const int nid = (int)__builtin_amdgcn_readfirstlane(Ew[256 + j]);

            uint32_t e[KNBR];
            #pragma unroll
            for (int k = 0; k < KNBR; ++k) e[k] = Ew[j * 16 + k];

            uint32_t hp;
            if (MODE >= 1) {
                hp = emb_bf[(size_t)nid * 64 + lane];
            } else {
                float2 hv = *(const float2*)(emb_f32 + (size_t)nid * 128 + 2 * lane);
                hp = bf16_rne(hv.x) | (bf16_rne(hv.y) << 16);
            }

            float ax = 0.f, ay = 0.f;

            if (MODE == 2) {
                uint32_t p[KNBR];
                #pragma unroll
                for (int k = 0; k < KNBR; ++k) {
                    const int sn = (int)(__builtin_amdgcn_readfirstlane(e[k]) & 0xFFFFFFu);
                    p[k] = (uint32_t)emb8[(size_t)sn * 64 + lane];   // 2 fp8 features
                }
                #pragma unroll
                for (int k = 0; k < KNBR; ++k) {
                    f32x2 d = __builtin_amdgcn_cvt_pk_f32_fp8(p[k], false);
                    ax += d.x; ay += d.y;
                }
            } else if (MODE == 1) {
                uint32_t p[KNBR];
                #pragma unroll
                for (int k = 0; k < KNBR; ++k) {
                    const int sn = (int)(__builtin_amdgcn_readfirstlane(e[k]) & 0xFFFFFFu);
                    p[k] = emb_bf[(size_t)sn * 64 + lane];
                }
                #pragma unroll
                for (int k = 0; k < KNBR; ++k) { ax += bf_lo(p[k]); ay += bf_hi(p[k]); }
            } else {
                #pragma unroll
                for (int k = 0; k < KNBR; ++k) {
                    const int sn = (int)(__builtin_amdgcn_readfirstlane(e[k]) & 0xFFFFFFu);
                    float2 v = *(const float2*)(emb_f32 + (size_t)sn * 128 + 2 * lane);
                    ax += v.x; ay += v.y;
                }
            }

            #pragma unroll
            for (int k = 0; k < KNBR; ++k) {
                const int bkt = (int)(__builtin_amdgcn_readfirstlane(e[k]) >> 24);
                float2 dv = *(const float2*)(dtab + bkt * 128 + 2 * lane);
                ax += dv.x; ay += dv.y;
            }

            ax *= 0.0625f; ay *= 0.0625f;
            Aw[j * A_STRIDE + (lane ^ sw)] = hp;                                       // cols 0..127 = h
            Aw[j * A_STRIDE + 64 + (lane ^ sw)] = bf16_rne(ax) | (bf16_rne(ay) << 16); // 128..255 = agg
        }

        asm volatile("s_waitcnt lgkmcnt(0)" ::: "memory");

        // ---- MFMA phase: 16 rows x 128 cols, K=256 ----
        f32x4 acc[8];
        #pragma unroll
        for (int t = 0; t < 8; ++t) acc[t] = (f32x4){0.f, 0.f, 0.f, 0.f};

        #pragma unroll
        for (int ks = 0; ks < 8; ++ks) {
            ABFrag a;  // A[row=l_lo][k = ks*32 + l_hi*8 + 0..7]
            a.u = *(const uint4*)(Aw + l_lo * A_STRIDE + ((ks * 16 + l_hi * 4) ^ ((l_lo & 7) << 2)));
            #pragma unroll
            for (int nt = 0; nt < 8; ++nt) {
                ABFrag b;  // packed weights, L2-hot
                b.u = ((const uint4*)Bp)[(ks * 8 + nt) * 64 + lane];
                acc[nt] = __builtin_amdgcn_mfma_f32_16x16x32_bf16(a.v, b.v, acc[nt], 0, 0, 0);
            }
        }

        // ---- epilogue: bias+relu -> LDS -> coalesced full-line stores ----
        #pragma unroll
        for (int nt = 0; nt < 8; ++nt) {
            const int col = nt * 16 + l_lo;
            const float bv = bsh[col];
            #pragma unroll
            for (int r = 0; r < 4; ++r) {
                float v = acc[nt][r] + bv;
                Fw[(l_hi * 4 + r) * A_STRIDE + col] = v > 0.f ? v : 0.f;
            }
        }
        float* dst = out + (size_t)tile * 2048;
        #pragma unroll
        for (int it = 0; it < 8; ++it) {
            const int f = it * 256 + lane * 4;
            const int r = f >> 7, c = f & 127;
            float4 v = *(const float4*)(Fw + r * A_STRIDE + c);
            *(float4*)(dst + f) = v;
        }
    }
}

// ---------- safety fallback (tiny ws / tail nodes) ----------
__global__ void k_naive(const int* __restrict__ node_ids, const int* __restrict__ nbr_idx,
                        const float* __restrict__ nbr_dist, const float* __restrict__ emb,
                        const float* __restrict__ dt, const float* __restrict__ Ws,
                        const float* __restrict__ Wn, const float* __restrict__ bias,
                        float* __restrict__ out, int base) {
    __shared__ float h[128], ag[128];
    const int nd = base + blockIdx.x;
    const int t = threadIdx.x;
    const int nid = node_ids[nd];
    float hv = emb[(size_t)nid * 128 + t];
    float a = 0.f;
    for (int k = 0; k < KNBR; ++k) {
        int sn = node_ids[nbr_idx[(size_t)nd * KNBR + k]];
        int bkt = bucket_of(nbr_dist[(size_t)nd * KNBR + k]);
        a += emb[(size_t)sn * 128 + t] + dt[bkt * 128 + t];
    }
    h[t] = hv; ag[t] = a * 0.0625f;
    __syncthreads();
    float s = bias[t];
    for (int d = 0; d < 128; ++d) s += h[d] * Ws[d * 128 + t] + ag[d] * Wn[d * 128 + t];
    out[(size_t)nd * 128 + t] = s > 0.f ? s : 0.f;
}

extern "C" void kernel_launch(void* const* d_in, const int* in_sizes, int n_in,
                              void* d_out, int out_size, void* d_ws, size_t ws_size,
                              hipStream_t stream) {
    const int* node_ids   = (const int*)d_in[0];
    const int* nbr_idx    = (const int*)d_in[1];
    const float* nbr_dist = (const float*)d_in[2];
    const float* emb      = (const float*)d_in[3];
    const float* dist_tab = (const float*)d_in[4];
    const float* Ws       = (const float*)d_in[5];
    const float* Wn       = (const float*)d_in[6];
    const float* bias     = (const float*)d_in[7];
    float* out = (float*)d_out;
    const int n = in_sizes[0];
    const int in_dim = in_sizes[3] / 128;

    const size_t offCnt = 65536;               // after 64KB packed-W
    const size_t offEbf = offCnt + 256;
    const size_t offE8  = offEbf + (size_t)in_dim * 128 * 2;
    const size_t needB  = offEbf;
    const size_t needE  = offE8;
    const size_t needF  = offE8 + (size_t)in_dim * 128;

    if (ws_size < needB) {
        if (n > 0)
            k_naive<<<n, 128, 0, stream>>>(node_ids, nbr_idx, nbr_dist, emb, dist_tab, Ws, Wn, bias, out, 0);
        return;
    }
    uint16_t* Bp   = (uint16_t*)d_ws;
    int* counter   = (int*)((char*)d_ws + offCnt);
    uint32_t* ebf  = (uint32_t*)((char*)d_ws + offEbf);
    uint32_t* e8   = (uint32_t*)((char*)d_ws + offE8);

    k_pack_w<<<128, 256, 0, stream>>>(Ws, Wn, Bp, counter);

    const int ntiles = n >> 4;
    const int rem = n & 15;

    if (ws_size >= needF) {
        k_cvt_both<<<2048, 256, 0, stream>>>(emb, ebf, e8, in_dim * 32);
        if (ntiles > 0)
            k_main<2><<<256, 1024, 0, stream>>>(node_ids, nbr_idx, nbr_dist, emb, ebf, (const uint16_t*)e8,
                                                dist_tab, bias, (const uint32_t*)Bp, counter, out, ntiles);
    } else if (ws_size >= needE) {
        // bf16-only table (reuse k_cvt_both is not possible without e8 space): pack bf16 via MODE 1
        k_cvt_both<<<2048, 256, 0, stream>>>(emb, ebf, ebf /*dummy overwrite-safe? no*/, 0); // no-op
        // fall back: build bf16 table with a grid-stride loop through MODE0-style conversion in k_main
        if (ntiles > 0)
            k_main<0><<<256, 1024, 0, stream>>>(node_ids, nbr_idx, nbr_dist, emb, ebf, (const uint16_t*)e8,
                                                dist_tab, bias, (const uint32_t*)Bp, counter, out, ntiles);
    } else {
        if (ntiles > 0)
            k_main<0><<<256, 1024, 0, stream>>>(node_ids, nbr_idx, nbr_dist, emb, ebf, (const uint16_t*)e8,
                                                dist_tab, bias, (const uint32_t*)Bp, counter, out, ntiles);
    }
    if (rem > 0)
        k_naive<<<rem, 128, 0, stream>>>(node_ids, nbr_idx, nbr_dist, emb, dist_tab, Ws, Wn, bias, out, ntiles << 4);
}

// Round 4
// 144.713 us; speedup vs baseline: 2.8974x; 1.3320x over previous
//
#include <hip/hip_runtime.h>
#include <stdint.h>

#define KNBR 16

typedef float f32x4 __attribute__((ext_vector_type(4)));
typedef float f32x2 __attribute__((ext_vector_type(2)));
typedef __bf16 bf16x8 __attribute__((ext_vector_type(8)));

union ABFrag { uint4 u; bf16x8 v; };

__device__ __forceinline__ uint32_t bf16_rne(float x) {
    uint32_t u = __float_as_uint(x);
    return (u + 0x7fffu + ((u >> 16) & 1u)) >> 16;
}
__device__ __forceinline__ float bf_lo(uint32_t p) { return __uint_as_float(p << 16); }
__device__ __forceinline__ float bf_hi(uint32_t p) { return __uint_as_float(p & 0xffff0000u); }

// searchsorted(BOUNDARIES=[1,2,4,8,16,32,64,128], d) = clamp(exp + (mant!=0), 0, 8)
__device__ __forceinline__ int bucket_of(float d) {
    uint32_t u = __float_as_uint(d);
    int e = (int)((u >> 23) & 0xff) - 127;
    int b = e + ((u & 0x7fffffu) != 0 ? 1 : 0);
    return min(max(b, 0), 8);
}

// ---------- prep: fp32 -> bf16 table AND fp8(e4m3) table in one read ----------
__global__ void k_cvt_both(const float* __restrict__ src, uint32_t* __restrict__ ebf,
                           uint32_t* __restrict__ e8, int n_dwords) {
    int i = blockIdx.x * blockDim.x + threadIdx.x;
    int stride = gridDim.x * blockDim.x;
    for (; i < n_dwords; i += stride) {
        float4 v = ((const float4*)src)[i];
        ebf[2 * i]     = bf16_rne(v.x) | (bf16_rne(v.y) << 16);
        ebf[2 * i + 1] = bf16_rne(v.z) | (bf16_rne(v.w) << 16);
        uint32_t p = 0;
        p = __builtin_amdgcn_cvt_pk_fp8_f32(v.x, v.y, p, false);
        p = __builtin_amdgcn_cvt_pk_fp8_f32(v.z, v.w, p, true);
        e8[i] = p;
    }
}

// ---------- prep: pack Wcat=[W_self;W_nbr] (256x128) into MFMA B-fragment order ----------
__global__ void k_pack_w(const float* __restrict__ Ws, const float* __restrict__ Wn,
                         uint16_t* __restrict__ Bp) {
    int o = blockIdx.x * blockDim.x + threadIdx.x;
    if (o >= 8 * 8 * 64 * 8) return;
    int i = o & 7, lane = (o >> 3) & 63, nt = (o >> 9) & 7, ks = o >> 12;
    int r = ks * 32 + (lane >> 4) * 8 + i;
    int c = nt * 16 + (lane & 15);
    float v = (r < 128) ? Ws[r * 128 + c] : Wn[(r - 128) * 128 + c];
    Bp[o] = (uint16_t)bf16_rne(v);
}

// ---------- fused main ----------
// MODE: 0 = f32 gathers (no ws tables), 2 = fp8 neighbors + bf16 self
#define A_STRIDE 132
template <int MODE>
__global__ __launch_bounds__(1024, 4) void k_main(
    const int* __restrict__ node_ids, const int* __restrict__ nbr_idx,
    const float* __restrict__ nbr_dist, const float* __restrict__ emb_f32,
    const uint32_t* __restrict__ emb_bf, const uint16_t* __restrict__ emb8,
    const float* __restrict__ dist_table, const float* __restrict__ bias,
    const uint32_t* __restrict__ Bp, float* __restrict__ out, int ntiles)
{
    __shared__ uint32_t As[16 * 16 * A_STRIDE];
    __shared__ uint32_t Es[16 * 272];         // per wave: 256 packed (sn|bkt<<24) + 16 self ids
    __shared__ float dtab[9 * 128];
    __shared__ float bsh[128];

    for (int t = threadIdx.x; t < 9 * 128; t += 1024) dtab[t] = dist_table[t];
    if (threadIdx.x < 128) bsh[threadIdx.x] = bias[threadIdx.x];
    __syncthreads();

    const int lane = threadIdx.x & 63;
    const int w = threadIdx.x >> 6;
    const int l_hi = lane >> 4;   // 0..3
    const int l_lo = lane & 15;   // 0..15
    uint32_t* Aw = As + w * (16 * A_STRIDE);
    uint32_t* Ew = Es + w * 272;
    float* Fw = (float*)(As) + w * (16 * A_STRIDE);

    const int wid = blockIdx.x * 16 + w;
    const int nwaves = gridDim.x * 16;

    // static round-robin tile assignment (no atomics)
    for (int tile = wid; tile < ntiles; tile += nwaves) {

        // ---- phase A: translate all 256 neighbor indices in parallel ----
        {
            int4 nb = *(const int4*)(nbr_idx + (size_t)tile * 256 + lane * 4);
            float4 dd = *(const float4*)(nbr_dist + (size_t)tile * 256 + lane * 4);
            int s0 = node_ids[nb.x];
            int s1 = node_ids[nb.y];
            int s2 = node_ids[nb.z];
            int s3 = node_ids[nb.w];
            uint4 e;
            e.x = (uint32_t)s0 | ((uint32_t)bucket_of(dd.x) << 24);
            e.y = (uint32_t)s1 | ((uint32_t)bucket_of(dd.y) << 24);
            e.z = (uint32_t)s2 | ((uint32_t)bucket_of(dd.z) << 24);
            e.w = (uint32_t)s3 | ((uint32_t)bucket_of(dd.w) << 24);
            *(uint4*)(Ew + lane * 4) = e;
            if (lane < 16) Ew[256 + lane] = (uint32_t)node_ids[(size_t)tile * 16 + lane];
        }

        // ---- phase B: per node, 17 independent row gathers (high MLP) ----
        #pragma unroll 2
        for (int j = 0; j < 16; ++j) {
            const int sw = (j & 7) << 2;
            const int nid = (int)__builtin_amdgcn_readfirstlane(Ew[256 + j]);

            uint32_t e[KNBR];
            #pragma unroll
            for (int k = 0; k < KNBR; ++k) e[k] = Ew[j * 16 + k];

            uint32_t hp;
            if (MODE >= 1) {
                hp = emb_bf[(size_t)nid * 64 + lane];
            } else {
                float2 hv = *(const float2*)(emb_f32 + (size_t)nid * 128 + 2 * lane);
                hp = bf16_rne(hv.x) | (bf16_rne(hv.y) << 16);
            }

            float ax = 0.f, ay = 0.f;

            if (MODE == 2) {
                uint32_t p[KNBR];
                #pragma unroll
                for (int k = 0; k < KNBR; ++k) {
                    const int sn = (int)(__builtin_amdgcn_readfirstlane(e[k]) & 0xFFFFFFu);
                    p[k] = (uint32_t)emb8[(size_t)sn * 64 + lane];   // 2 fp8 features
                }
                #pragma unroll
                for (int k = 0; k < KNBR; ++k) {
                    f32x2 d = __builtin_amdgcn_cvt_pk_f32_fp8(p[k], false);
                    ax += d.x; ay += d.y;
                }
            } else {
                #pragma unroll
                for (int k = 0; k < KNBR; ++k) {
                    const int sn = (int)(__builtin_amdgcn_readfirstlane(e[k]) & 0xFFFFFFu);
                    float2 v = *(const float2*)(emb_f32 + (size_t)sn * 128 + 2 * lane);
                    ax += v.x; ay += v.y;
                }
            }

            #pragma unroll
            for (int k = 0; k < KNBR; ++k) {
                const int bkt = (int)(__builtin_amdgcn_readfirstlane(e[k]) >> 24);
                float2 dv = *(const float2*)(dtab + bkt * 128 + 2 * lane);
                ax += dv.x; ay += dv.y;
            }

            ax *= 0.0625f; ay *= 0.0625f;
            Aw[j * A_STRIDE + (lane ^ sw)] = hp;                                       // cols 0..127 = h
            Aw[j * A_STRIDE + 64 + (lane ^ sw)] = bf16_rne(ax) | (bf16_rne(ay) << 16); // 128..255 = agg
        }

        asm volatile("s_waitcnt lgkmcnt(0)" ::: "memory");

        // ---- MFMA phase: 16 rows x 128 cols, K=256 ----
        f32x4 acc[8];
        #pragma unroll
        for (int t = 0; t < 8; ++t) acc[t] = (f32x4){0.f, 0.f, 0.f, 0.f};

        #pragma unroll
        for (int ks = 0; ks < 8; ++ks) {
            ABFrag a;  // A[row=l_lo][k = ks*32 + l_hi*8 + 0..7]
            a.u = *(const uint4*)(Aw + l_lo * A_STRIDE + ((ks * 16 + l_hi * 4) ^ ((l_lo & 7) << 2)));
            #pragma unroll
            for (int nt = 0; nt < 8; ++nt) {
                ABFrag b;  // packed weights, L2-hot
                b.u = ((const uint4*)Bp)[(ks * 8 + nt) * 64 + lane];
                acc[nt] = __builtin_amdgcn_mfma_f32_16x16x32_bf16(a.v, b.v, acc[nt], 0, 0, 0);
            }
        }

        // ---- epilogue: bias+relu -> LDS -> coalesced full-line stores ----
        #pragma unroll
        for (int nt = 0; nt < 8; ++nt) {
            const int col = nt * 16 + l_lo;
            const float bv = bsh[col];
            #pragma unroll
            for (int r = 0; r < 4; ++r) {
                float v = acc[nt][r] + bv;
                Fw[(l_hi * 4 + r) * A_STRIDE + col] = v > 0.f ? v : 0.f;
            }
        }
        float* dst = out + (size_t)tile * 2048;
        #pragma unroll
        for (int it = 0; it < 8; ++it) {
            const int f = it * 256 + lane * 4;
            const int r = f >> 7, c = f & 127;
            float4 v = *(const float4*)(Fw + r * A_STRIDE + c);
            *(float4*)(dst + f) = v;
        }
    }
}

// ---------- safety fallback (tiny ws / tail nodes) ----------
__global__ void k_naive(const int* __restrict__ node_ids, const int* __restrict__ nbr_idx,
                        const float* __restrict__ nbr_dist, const float* __restrict__ emb,
                        const float* __restrict__ dt, const float* __restrict__ Ws,
                        const float* __restrict__ Wn, const float* __restrict__ bias,
                        float* __restrict__ out, int base) {
    __shared__ float h[128], ag[128];
    const int nd = base + blockIdx.x;
    const int t = threadIdx.x;
    const int nid = node_ids[nd];
    float hv = emb[(size_t)nid * 128 + t];
    float a = 0.f;
    for (int k = 0; k < KNBR; ++k) {
        int sn = node_ids[nbr_idx[(size_t)nd * KNBR + k]];
        int bkt = bucket_of(nbr_dist[(size_t)nd * KNBR + k]);
        a += emb[(size_t)sn * 128 + t] + dt[bkt * 128 + t];
    }
    h[t] = hv; ag[t] = a * 0.0625f;
    __syncthreads();
    float s = bias[t];
    for (int d = 0; d < 128; ++d) s += h[d] * Ws[d * 128 + t] + ag[d] * Wn[d * 128 + t];
    out[(size_t)nd * 128 + t] = s > 0.f ? s : 0.f;
}

extern "C" void kernel_launch(void* const* d_in, const int* in_sizes, int n_in,
                              void* d_out, int out_size, void* d_ws, size_t ws_size,
                              hipStream_t stream) {
    const int* node_ids   = (const int*)d_in[0];
    const int* nbr_idx    = (const int*)d_in[1];
    const float* nbr_dist = (const float*)d_in[2];
    const float* emb      = (const float*)d_in[3];
    const float* dist_tab = (const float*)d_in[4];
    const float* Ws       = (const float*)d_in[5];
    const float* Wn       = (const float*)d_in[6];
    const float* bias     = (const float*)d_in[7];
    float* out = (float*)d_out;
    const int n = in_sizes[0];
    const int in_dim = in_sizes[3] / 128;

    const size_t offEbf = 65536;               // after 64KB packed-W
    const size_t offE8  = offEbf + (size_t)in_dim * 128 * 2;
    const size_t needB  = offEbf;
    const size_t needF  = offE8 + (size_t)in_dim * 128;

    if (ws_size < needB) {
        if (n > 0)
            k_naive<<<n, 128, 0, stream>>>(node_ids, nbr_idx, nbr_dist, emb, dist_tab, Ws, Wn, bias, out, 0);
        return;
    }
    uint16_t* Bp   = (uint16_t*)d_ws;
    uint32_t* ebf  = (uint32_t*)((char*)d_ws + offEbf);
    uint32_t* e8   = (uint32_t*)((char*)d_ws + offE8);

    k_pack_w<<<128, 256, 0, stream>>>(Ws, Wn, Bp);

    const int ntiles = n >> 4;
    const int rem = n & 15;

    if (ws_size >= needF) {
        k_cvt_both<<<2048, 256, 0, stream>>>(emb, ebf, e8, in_dim * 32);
        if (ntiles > 0)
            k_main<2><<<256, 1024, 0, stream>>>(node_ids, nbr_idx, nbr_dist, emb, ebf, (const uint16_t*)e8,
                                                dist_tab, bias, (const uint32_t*)Bp, out, ntiles);
    } else {
        if (ntiles > 0)
            k_main<0><<<256, 1024, 0, stream>>>(node_ids, nbr_idx, nbr_dist, emb, ebf, (const uint16_t*)e8,
                                                dist_tab, bias, (const uint32_t*)Bp, out, ntiles);
    }
    if (rem > 0)
        k_naive<<<rem, 128, 0, stream>>>(node_ids, nbr_idx, nbr_dist, emb, dist_tab, Ws, Wn, bias, out, ntiles << 4);
}

// Round 5
// 139.449 us; speedup vs baseline: 3.0068x; 1.0377x over previous
//
#include <hip/hip_runtime.h>
#include <stdint.h>

#define KNBR 16

typedef float f32x4 __attribute__((ext_vector_type(4)));
typedef float f32x2 __attribute__((ext_vector_type(2)));
typedef __bf16 bf16x8 __attribute__((ext_vector_type(8)));

union ABFrag { uint4 u; bf16x8 v; };

__device__ __forceinline__ uint32_t bf16_rne(float x) {
    uint32_t u = __float_as_uint(x);
    return (u + 0x7fffu + ((u >> 16) & 1u)) >> 16;
}

// searchsorted(BOUNDARIES=[1,2,4,8,16,32,64,128], d) = clamp(exp + (mant!=0), 0, 8)
__device__ __forceinline__ uint32_t bucket_of(float d) {
    uint32_t u = __float_as_uint(d);
    int e = (int)((u >> 23) & 0xff) - 127;
    int b = e + ((u & 0x7fffffu) != 0 ? 1 : 0);
    return (uint32_t)min(max(b, 0), 8);
}

// ---------- prep: fp32 -> bf16 table AND fp8(e4m3) table in one read ----------
__global__ void k_cvt_both(const float* __restrict__ src, uint32_t* __restrict__ ebf,
                           uint32_t* __restrict__ e8, int n_dwords) {
    int i = blockIdx.x * blockDim.x + threadIdx.x;
    int stride = gridDim.x * blockDim.x;
    for (; i < n_dwords; i += stride) {
        float4 v = ((const float4*)src)[i];
        ebf[2 * i]     = bf16_rne(v.x) | (bf16_rne(v.y) << 16);
        ebf[2 * i + 1] = bf16_rne(v.z) | (bf16_rne(v.w) << 16);
        uint32_t p = 0;
        p = __builtin_amdgcn_cvt_pk_fp8_f32(v.x, v.y, p, false);
        p = __builtin_amdgcn_cvt_pk_fp8_f32(v.z, v.w, p, true);
        e8[i] = p;
    }
}

// ---------- prep: pack Wcat=[W_self;W_nbr] (256x128) into MFMA B-fragment order ----------
__global__ void k_pack_w(const float* __restrict__ Ws, const float* __restrict__ Wn,
                         uint16_t* __restrict__ Bp) {
    int o = blockIdx.x * blockDim.x + threadIdx.x;
    if (o >= 8 * 8 * 64 * 8) return;
    int i = o & 7, lane = (o >> 3) & 63, nt = (o >> 9) & 7, ks = o >> 12;
    int r = ks * 32 + (lane >> 4) * 8 + i;
    int c = nt * 16 + (lane & 15);
    float v = (r < 128) ? Ws[r * 128 + c] : Wn[(r - 128) * 128 + c];
    Bp[o] = (uint16_t)bf16_rne(v);
}

// ---------- fused main: SGPR-uniform gathers + register dist-table ----------
#define A_STRIDE 132
__global__ __launch_bounds__(1024, 4) void k_main(
    const int* __restrict__ node_ids, const int* __restrict__ nbr_idx,
    const float* __restrict__ nbr_dist,
    const uint32_t* __restrict__ emb_bf, const uint16_t* __restrict__ emb8,
    const float* __restrict__ dist_table, const float* __restrict__ bias,
    const uint32_t* __restrict__ Bp, float* __restrict__ out, int ntiles)
{
    __shared__ uint32_t As[16 * 16 * A_STRIDE];   // 16 waves x (16 rows x 256 bf16)
    __shared__ float bsh[128];

    if (threadIdx.x < 128) bsh[threadIdx.x] = bias[threadIdx.x];
    __syncthreads();

    const int lane = threadIdx.x & 63;
    const int w = threadIdx.x >> 6;
    const int l_hi = lane >> 4;   // 0..3
    const int l_lo = lane & 15;   // 0..15
    uint32_t* Aw = As + w * (16 * A_STRIDE);
    float* Fw = (float*)(As) + w * (16 * A_STRIDE);

    // per-lane dist-table registers: 9 buckets x float2 (features 2*lane, 2*lane+1)
    float2 dreg[9];
    #pragma unroll
    for (int b = 0; b < 9; ++b)
        dreg[b] = *(const float2*)(dist_table + b * 128 + 2 * lane);

    const int wid = blockIdx.x * 16 + w;
    const int nwaves = gridDim.x * 16;

    for (int tile = wid; tile < ntiles; tile += nwaves) {

        // ---- phase A: per-lane translate 4 neighbors; keep in registers ----
        int4 nb = *(const int4*)(nbr_idx + (size_t)tile * 256 + lane * 4);
        float4 dd = *(const float4*)(nbr_dist + (size_t)tile * 256 + lane * 4);
        uint32_t ea[4];
        ea[0] = (uint32_t)node_ids[nb.x] | (bucket_of(dd.x) << 24);
        ea[1] = (uint32_t)node_ids[nb.y] | (bucket_of(dd.y) << 24);
        ea[2] = (uint32_t)node_ids[nb.z] | (bucket_of(dd.z) << 24);
        ea[3] = (uint32_t)node_ids[nb.w] | (bucket_of(dd.w) << 24);
        uint32_t selfv = (uint32_t)node_ids[(size_t)tile * 16 + (lane & 15)];

        // ---- phase B: per node j, wave-uniform row gathers (SGPR base), scalar histogram ----
        #pragma unroll
        for (int j = 0; j < 16; ++j) {
            const int sw = (j & 7) << 2;
            const uint32_t sid = (uint32_t)__builtin_amdgcn_readlane((int)selfv, j);
            const uint32_t hp = emb_bf[(size_t)sid * 64 + lane];   // saddr + lane*4

            uint64_t cnt = 0;                // 9 buckets x 5-bit counts (scalar)
            uint32_t p[KNBR];
            #pragma unroll
            for (int k = 0; k < KNBR; ++k) {
                const uint32_t ew = (uint32_t)__builtin_amdgcn_readlane((int)ea[k & 3], 4 * j + (k >> 2));
                const uint32_t sn = ew & 0xFFFFFFu;
                cnt += 1ull << (5 * (ew >> 24));
                p[k] = (uint32_t)emb8[(size_t)sn * 64 + lane];     // saddr + lane*2, 1 line/wave
            }

            float ax = 0.f, ay = 0.f;
            #pragma unroll
            for (int k = 0; k < KNBR; ++k) {
                f32x2 d = __builtin_amdgcn_cvt_pk_f32_fp8(p[k], false);
                ax += d.x; ay += d.y;
            }
            #pragma unroll
            for (int b = 0; b < 9; ++b) {
                const float fb = (float)(uint32_t)((cnt >> (5 * b)) & 31u);
                ax += fb * dreg[b].x;
                ay += fb * dreg[b].y;
            }
            ax *= 0.0625f; ay *= 0.0625f;

            Aw[j * A_STRIDE + (lane ^ sw)] = hp;                                       // cols 0..127 = h
            Aw[j * A_STRIDE + 64 + (lane ^ sw)] = bf16_rne(ax) | (bf16_rne(ay) << 16); // 128..255 = agg
        }

        asm volatile("s_waitcnt lgkmcnt(0)" ::: "memory");

        // ---- MFMA phase: 16 rows x 128 cols, K=256 ----
        f32x4 acc[8];
        #pragma unroll
        for (int t = 0; t < 8; ++t) acc[t] = (f32x4){0.f, 0.f, 0.f, 0.f};

        #pragma unroll
        for (int ks = 0; ks < 8; ++ks) {
            ABFrag a;  // A[row=l_lo][k = ks*32 + l_hi*8 + 0..7]
            a.u = *(const uint4*)(Aw + l_lo * A_STRIDE + ((ks * 16 + l_hi * 4) ^ ((l_lo & 7) << 2)));
            #pragma unroll
            for (int nt = 0; nt < 8; ++nt) {
                ABFrag b;  // packed weights, L2-hot
                b.u = ((const uint4*)Bp)[(ks * 8 + nt) * 64 + lane];
                acc[nt] = __builtin_amdgcn_mfma_f32_16x16x32_bf16(a.v, b.v, acc[nt], 0, 0, 0);
            }
        }

        // ---- epilogue: bias+relu -> LDS -> coalesced full-line stores ----
        #pragma unroll
        for (int nt = 0; nt < 8; ++nt) {
            const int col = nt * 16 + l_lo;
            const float bv = bsh[col];
            #pragma unroll
            for (int r = 0; r < 4; ++r) {
                float v = acc[nt][r] + bv;
                Fw[(l_hi * 4 + r) * A_STRIDE + col] = v > 0.f ? v : 0.f;
            }
        }
        float* dst = out + (size_t)tile * 2048;
        #pragma unroll
        for (int it = 0; it < 8; ++it) {
            const int f = it * 256 + lane * 4;
            const int r = f >> 7, c = f & 127;
            float4 v = *(const float4*)(Fw + r * A_STRIDE + c);
            *(float4*)(dst + f) = v;
        }
    }
}

// ---------- safety fallback (tiny ws / tail nodes) ----------
__global__ void k_naive(const int* __restrict__ node_ids, const int* __restrict__ nbr_idx,
                        const float* __restrict__ nbr_dist, const float* __restrict__ emb,
                        const float* __restrict__ dt, const float* __restrict__ Ws,
                        const float* __restrict__ Wn, const float* __restrict__ bias,
                        float* __restrict__ out, int base) {
    __shared__ float h[128], ag[128];
    const int nd = base + blockIdx.x;
    const int t = threadIdx.x;
    const int nid = node_ids[nd];
    float hv = emb[(size_t)nid * 128 + t];
    float a = 0.f;
    for (int k = 0; k < KNBR; ++k) {
        int sn = node_ids[nbr_idx[(size_t)nd * KNBR + k]];
        int bkt = (int)bucket_of(nbr_dist[(size_t)nd * KNBR + k]);
        a += emb[(size_t)sn * 128 + t] + dt[bkt * 128 + t];
    }
    h[t] = hv; ag[t] = a * 0.0625f;
    __syncthreads();
    float s = bias[t];
    for (int d = 0; d < 128; ++d) s += h[d] * Ws[d * 128 + t] + ag[d] * Wn[d * 128 + t];
    out[(size_t)nd * 128 + t] = s > 0.f ? s : 0.f;
}

extern "C" void kernel_launch(void* const* d_in, const int* in_sizes, int n_in,
                              void* d_out, int out_size, void* d_ws, size_t ws_size,
                              hipStream_t stream) {
    const int* node_ids   = (const int*)d_in[0];
    const int* nbr_idx    = (const int*)d_in[1];
    const float* nbr_dist = (const float*)d_in[2];
    const float* emb      = (const float*)d_in[3];
    const float* dist_tab = (const float*)d_in[4];
    const float* Ws       = (const float*)d_in[5];
    const float* Wn       = (const float*)d_in[6];
    const float* bias     = (const float*)d_in[7];
    float* out = (float*)d_out;
    const int n = in_sizes[0];
    const int in_dim = in_sizes[3] / 128;

    const size_t offEbf = 65536;               // after 64KB packed-W
    const size_t offE8  = offEbf + (size_t)in_dim * 128 * 2;
    const size_t needF  = offE8 + (size_t)in_dim * 128;

    if (ws_size < needF) {
        if (n > 0)
            k_naive<<<n, 128, 0, stream>>>(node_ids, nbr_idx, nbr_dist, emb, dist_tab, Ws, Wn, bias, out, 0);
        return;
    }
    uint16_t* Bp   = (uint16_t*)d_ws;
    uint32_t* ebf  = (uint32_t*)((char*)d_ws + offEbf);
    uint32_t* e8   = (uint32_t*)((char*)d_ws + offE8);

    k_pack_w<<<128, 256, 0, stream>>>(Ws, Wn, Bp);
    k_cvt_both<<<2048, 256, 0, stream>>>(emb, ebf, e8, in_dim * 32);

    const int ntiles = n >> 4;
    const int rem = n & 15;

    if (ntiles > 0)
        k_main<<<256, 1024, 0, stream>>>(node_ids, nbr_idx, nbr_dist, ebf, (const uint16_t*)e8,
                                         dist_tab, bias, (const uint32_t*)Bp, out, ntiles);
    if (rem > 0)
        k_naive<<<rem, 128, 0, stream>>>(node_ids, nbr_idx, nbr_dist, emb, dist_tab, Ws, Wn, bias, out, ntiles << 4);
}